// Round 11
// baseline (536.644 us; speedup 1.0000x reference)
//
#include <hip/hip_runtime.h>

#define B_ 64
#define N_ 196
#define C_ 768
#define H_ 16
#define DFF_ 3072
#define M_ (B_ * N_)  // 12544

typedef float f32x4 __attribute__((ext_vector_type(4)));
typedef __bf16 bf16x8 __attribute__((ext_vector_type(8)));
typedef unsigned short u16;
typedef unsigned short u16x8 __attribute__((ext_vector_type(8)));

__device__ __forceinline__ u16 f2bf(float f) {
  unsigned u = __float_as_uint(f);
  unsigned r = (u + 0x7FFFu + ((u >> 16) & 1u)) >> 16;  // RTNE
  return (u16)r;
}
__device__ __forceinline__ float bf2f(u16 h) {
  return __uint_as_float(((unsigned)h) << 16);
}

// async global->LDS, 16B per lane; LDS base must be wave-uniform (HW: base + lane*16)
__device__ __forceinline__ void gload_lds16(const u16* g, u16* l) {
  typedef const __attribute__((address_space(1))) void gp_t;
  typedef __attribute__((address_space(3))) void lp_t;
  __builtin_amdgcn_global_load_lds((gp_t*)g, (lp_t*)l, 16, 0, 0);
}

// ---------------- diagnostic sentinel fill (ws_size guard path) ----------------
__global__ __launch_bounds__(256) void fill_sentinel(float* __restrict__ out, int n) {
  for (int i = blockIdx.x * 256 + threadIdx.x; i < n; i += gridDim.x * 256)
    out[i] = 12345.0f;
}

// ---------------- f32 -> bf16 weight conversion (x4 vectorized) ----------------
__global__ __launch_bounds__(256) void f2b4(const float4* __restrict__ in,
                                            ushort4* __restrict__ out, int n4) {
  for (int i = blockIdx.x * 256 + threadIdx.x; i < n4; i += gridDim.x * 256) {
    float4 v = in[i];
    ushort4 o;
    o.x = f2bf(v.x); o.y = f2bf(v.y); o.z = f2bf(v.z); o.w = f2bf(v.w);
    out[i] = o;
  }
}

// ---------------- LayerNorm over rows of 768: f32 in -> bf16 out ----------------
__global__ __launch_bounds__(256) void ln_rows(const float* __restrict__ x,
                                               const float* __restrict__ w,
                                               const float* __restrict__ b,
                                               u16* __restrict__ out) {
  const int row = blockIdx.x;
  const int t = threadIdx.x;
  const float* xr = x + (size_t)row * C_;
  float v0 = xr[t], v1 = xr[t + 256], v2 = xr[t + 512];
  float s = v0 + v1 + v2;
  float s2 = v0 * v0 + v1 * v1 + v2 * v2;
#pragma unroll
  for (int o = 32; o; o >>= 1) { s += __shfl_xor(s, o); s2 += __shfl_xor(s2, o); }
  __shared__ float rbuf[8];
  const int wid = t >> 6;
  if ((t & 63) == 0) { rbuf[wid] = s; rbuf[wid + 4] = s2; }
  __syncthreads();
  s = rbuf[0] + rbuf[1] + rbuf[2] + rbuf[3];
  s2 = rbuf[4] + rbuf[5] + rbuf[6] + rbuf[7];
  const float mu = s * (1.f / C_);
  const float inv = rsqrtf(s2 * (1.f / C_) - mu * mu + 1e-5f);
  u16* orow = out + (size_t)row * C_;
  orow[t]       = f2bf((v0 - mu) * inv * w[t]       + b[t]);
  orow[t + 256] = f2bf((v1 - mu) * inv * w[t + 256] + b[t + 256]);
  orow[t + 512] = f2bf((v2 - mu) * inv * w[t + 512] + b[t + 512]);
}

// ---------------- positional softmax: [H,N,N] fp32, input-independent of x ----------------
__global__ __launch_bounds__(64) void pos_softmax(const float* __restrict__ pos_w,
                                                  const float* __restrict__ pos_b,
                                                  float* __restrict__ pos) {
  const int i = blockIdx.x;  // 0..195
  const int h = blockIdx.y;  // 0..15
  const int lane = threadIdx.x;
  const float w0 = pos_w[h * 3], w1 = pos_w[h * 3 + 1], w2 = pos_w[h * 3 + 2];
  const float bb = pos_b[h];
  const int iy = i / 14, ix = i % 14;
  float lg[4];
#pragma unroll
  for (int c = 0; c < 4; ++c) {
    const int j = lane + c * 64;
    if (j < N_) {
      const int jy = j / 14, jx = j % 14;
      const float dx = (float)(jx - ix), dy = (float)(jy - iy);
      lg[c] = dx * w0 + dy * w1 + (dx * dx + dy * dy) * w2 + bb;
    } else lg[c] = -3.4e38f;
  }
  float mx = fmaxf(fmaxf(lg[0], lg[1]), fmaxf(lg[2], lg[3]));
#pragma unroll
  for (int o = 32; o; o >>= 1) mx = fmaxf(mx, __shfl_xor(mx, o));
  float sum = 0.f;
#pragma unroll
  for (int c = 0; c < 4; ++c) {
    lg[c] = (lane + c * 64 < N_) ? expf(lg[c] - mx) : 0.f;
    sum += lg[c];
  }
#pragma unroll
  for (int o = 32; o; o >>= 1) sum += __shfl_xor(sum, o);
  const float inv = 1.f / sum;
  float* prow = pos + ((size_t)h * N_ + i) * N_;
#pragma unroll
  for (int c = 0; c < 4; ++c) {
    const int j = lane + c * 64;
    if (j < N_) prow[j] = lg[c] * inv;
  }
}

// ---------------- bf16 MFMA GEMM: C[M,Nn] = A[M,K] @ Bw[Nn,K]^T ----------------
// 128x128 tile, 4 waves, BK=64, T3-minimum 2-phase with LDS DOUBLE BUFFER:
//   prologue: stage(buf0, t0); __syncthreads (drains vmcnt);
//   loop:     stage(buf^1, t+1) issue-first; ds_read+MFMA from buf;
//             __syncthreads (drains vmcnt+lgkm, one barrier per K-tile); swap.
// 64KB LDS -> 2 blocks/CU (cross-block overlap, m114 mechanism).
// LDS XOR-swizzle via pre-swizzled global source (verified pair from round 8):
// LDS[row][s] holds global slot s^(row&7); read slot = q^(row&7). 2-way free.
// EPI 0: bf16. 1: f32 acc+bias+res. 2: bf16 gelu(acc+bias).
#define BM 128
#define BN 128
#define BK 64

template <int EPI>
__global__ __launch_bounds__(256, 2) void gemm_bt(
    const u16* __restrict__ A, const u16* __restrict__ Bw, void* __restrict__ Cout,
    const float* __restrict__ bias, const float* __restrict__ res,
    int M, int Nn, int K) {
  __shared__ __align__(16) u16 lds[2][2][BM * BK];  // [buf][A|B][128x64]
  const int t = threadIdx.x;
  const int lane = t & 63;
  const int wid = t >> 6;
  const int wr = wid >> 1, wc = wid & 1;
  const int brow = blockIdx.y * BM;
  const int bcol = blockIdx.x * BN;
  const int r16 = lane & 15;  // fragment row/col within 16
  const int kg = lane >> 4;   // k-group 0..3

  const int srow = lane >> 3;                 // staging row within 8-row chunk
  const int scol = 8 * ((lane & 7) ^ srow);   // pre-swizzled global col (elems)

  auto stage = [&](int buf, int k0) {
#pragma unroll
    for (int i = 0; i < 4; ++i) {
      const int c = wid * 4 + i;      // chunk 0..15 (1KB each)
      const int row = c * 8 + srow;   // 0..127
      gload_lds16(&A[(size_t)(brow + row) * K + k0 + scol], &lds[buf][0][c * 512]);
      gload_lds16(&Bw[(size_t)(bcol + row) * K + k0 + scol], &lds[buf][1][c * 512]);
    }
  };

  f32x4 acc[4][4] = {};
  const int nt = K / BK;

  stage(0, 0);
  __syncthreads();  // vmcnt(0) drain: tile0 resident
  int buf = 0;
  for (int tt = 0; tt < nt; ++tt) {
    if (tt + 1 < nt) stage(buf ^ 1, (tt + 1) * BK);  // issue early, lands by barrier
#pragma unroll
    for (int kk = 0; kk < 2; ++kk) {
      bf16x8 af[4], bfr[4];
#pragma unroll
      for (int m = 0; m < 4; ++m) {
        const int r = wr * 64 + m * 16 + r16;
        af[m] = *reinterpret_cast<const bf16x8*>(
            &lds[buf][0][r * BK + 8 * ((kk * 4 + kg) ^ (r & 7))]);
      }
#pragma unroll
      for (int n = 0; n < 4; ++n) {
        const int r = wc * 64 + n * 16 + r16;
        bfr[n] = *reinterpret_cast<const bf16x8*>(
            &lds[buf][1][r * BK + 8 * ((kk * 4 + kg) ^ (r & 7))]);
      }
#pragma unroll
      for (int m = 0; m < 4; ++m)
#pragma unroll
        for (int n = 0; n < 4; ++n)
          acc[m][n] = __builtin_amdgcn_mfma_f32_16x16x32_bf16(af[m], bfr[n], acc[m][n], 0, 0, 0);
    }
    __syncthreads();  // single barrier per K-tile: drains vmcnt (next tile) + readers done
    buf ^= 1;
  }

#pragma unroll
  for (int m = 0; m < 4; ++m) {
#pragma unroll
    for (int n = 0; n < 4; ++n) {
#pragma unroll
      for (int r = 0; r < 4; ++r) {
        const int row = brow + wr * 64 + m * 16 + kg * 4 + r;
        const int col = bcol + wc * 64 + n * 16 + r16;
        const float v = acc[m][n][r];
        if (EPI == 0) {
          ((u16*)Cout)[(size_t)row * Nn + col] = f2bf(v);
        } else if (EPI == 1) {
          ((float*)Cout)[(size_t)row * Nn + col] = v + bias[col] + res[(size_t)row * Nn + col];
        } else {
          const float u = v + bias[col];
          ((u16*)Cout)[(size_t)row * Nn + col] =
              f2bf(0.5f * u * (1.f + erff(u * 0.70710678118654752f)));
        }
      }
    }
  }
}

// ---------------- MFMA GPSA attention: 8 waves, <=2 mt-tiles per wave --------
// P stride 228 (456B: row*18 mod 32 distinct over 8 rows -> 2-way free),
// VT stride 232. LDS = 48*232*2 + 8*16*228*2 = 78.75KB -> 2 blocks/CU.
#define PSTRV 232
#define PSTRP 228

__global__ __launch_bounds__(512, 1) void attn_mfma(const u16* __restrict__ qkv,
                                                    const float* __restrict__ pos,
                                                    const float* __restrict__ gating,
                                                    u16* __restrict__ out) {
  const int bh = blockIdx.x;
  const int b = bh >> 4, h = bh & 15;
  __shared__ __align__(16) u16 VT[48][PSTRV];
  __shared__ __align__(16) u16 P[8][16][PSTRP];
  const int t = threadIdx.x, lane = t & 63, w = t >> 6;
  const int c16 = lane & 15, g = lane >> 4;

  // stage V^T: (j, c8) -> VT[c8*8+e][j]
  for (int idx = t; idx < N_ * 6; idx += 512) {
    const int j = idx / 6, c8 = idx % 6;
    const u16x8 v = *reinterpret_cast<const u16x8*>(
        &qkv[((size_t)(b * N_ + j)) * 2304 + 1536 + h * 48 + c8 * 8]);
#pragma unroll
    for (int e = 0; e < 8; ++e) VT[c8 * 8 + e][j] = v[e];
  }
  // zero pad cols 196..231 of VT (18 dwords per row)
  for (int idx = t; idx < 48 * 18; idx += 512) {
    const int d = idx / 18, q = idx % 18;
    *reinterpret_cast<unsigned*>(&VT[d][196 + q * 2]) = 0u;
  }
  // zero pad cols 196..227 of all P stripes (16 dwords per row)
  for (int idx = t; idx < 8 * 16 * 16; idx += 512) {
    const int wv = idx / (16 * 16), rr = (idx / 16) % 16, q = idx % 16;
    *reinterpret_cast<unsigned*>(&P[wv][rr][196 + q * 2]) = 0u;
  }
  __syncthreads();

  const float sig = 1.f / (1.f + __expf(-gating[h]));
  const float scale = 0.14433756729740643f;  // 48^-0.5
  const float* poshp = pos + (size_t)h * N_ * N_;

  for (int mt = w; mt < 13; mt += 8) {
    bf16x8 qa0, qa1;
    {
      const int irow = mt * 16 + c16;
      const u16* qp = &qkv[((size_t)(b * N_ + irow)) * 2304 + h * 48];
      qa0 = *reinterpret_cast<const bf16x8*>(qp + g * 8);
      if (g < 2) qa1 = *reinterpret_cast<const bf16x8*>(qp + 32 + g * 8);
      else       qa1 = bf16x8{};  // zero k-pad 48..63
    }

    f32x4 s[13];
#pragma unroll
    for (int nt = 0; nt < 13; ++nt) {
      const int jrow = nt * 16 + c16;
      const u16* kp = &qkv[((size_t)(b * N_ + jrow)) * 2304 + 768 + h * 48];
      const bf16x8 kb0 = *reinterpret_cast<const bf16x8*>(kp + g * 8);
      const bf16x8 kb1 = *reinterpret_cast<const bf16x8*>(kp + 32 + g * 8);
      f32x4 acc = {};
      acc = __builtin_amdgcn_mfma_f32_16x16x32_bf16(qa0, kb0, acc, 0, 0, 0);
      acc = __builtin_amdgcn_mfma_f32_16x16x32_bf16(qa1, kb1, acc, 0, 0, 0);
      s[nt] = acc;
    }

    float mx[4] = {-3.4e38f, -3.4e38f, -3.4e38f, -3.4e38f};
#pragma unroll
    for (int nt = 0; nt < 13; ++nt)
#pragma unroll
      for (int r = 0; r < 4; ++r) {
        float v = s[nt][r];
        if (nt == 12 && c16 >= 4) v = -3.4e38f;  // col pad
        s[nt][r] = v;
        mx[r] = fmaxf(mx[r], v);
      }
#pragma unroll
    for (int r = 0; r < 4; ++r)
#pragma unroll
      for (int o = 1; o < 16; o <<= 1) mx[r] = fmaxf(mx[r], __shfl_xor(mx[r], o));

    float sum[4] = {0.f, 0.f, 0.f, 0.f};
#pragma unroll
    for (int nt = 0; nt < 13; ++nt)
#pragma unroll
      for (int r = 0; r < 4; ++r) {
        const float p = __expf((s[nt][r] - mx[r]) * scale);
        s[nt][r] = p;
        sum[r] += p;
      }
#pragma unroll
    for (int r = 0; r < 4; ++r) {
#pragma unroll
      for (int o = 1; o < 16; o <<= 1) sum[r] += __shfl_xor(sum[r], o);
      sum[r] = (1.f - sig) / sum[r];
    }

    float tot[4] = {0.f, 0.f, 0.f, 0.f};
    const int i0g = mt * 16 + 4 * g;
#pragma unroll
    for (int nt = 0; nt < 13; ++nt) {
      const int j = nt * 16 + c16;
#pragma unroll
      for (int r = 0; r < 4; ++r) {
        const int i = i0g + r;
        float pv = 0.f;
        if (i < N_ && j < N_) pv = poshp[(size_t)i * N_ + j];
        float a = s[nt][r] * sum[r] + sig * pv;
        if (j >= N_) a = 0.f;
        s[nt][r] = a;
        tot[r] += a;
      }
    }
#pragma unroll
    for (int r = 0; r < 4; ++r) {
#pragma unroll
      for (int o = 1; o < 16; o <<= 1) tot[r] += __shfl_xor(tot[r], o);
      tot[r] = 1.f / tot[r];
    }

#pragma unroll
    for (int nt = 0; nt < 13; ++nt)
#pragma unroll
      for (int r = 0; r < 4; ++r)
        P[w][4 * g + r][nt * 16 + c16] = f2bf(s[nt][r] * tot[r]);

    f32x4 oacc[3] = {};
#pragma unroll
    for (int kk2 = 0; kk2 < 7; ++kk2) {
      const bf16x8 pa = *reinterpret_cast<const bf16x8*>(&P[w][c16][kk2 * 32 + g * 8]);
#pragma unroll
      for (int dt = 0; dt < 3; ++dt) {
        const bf16x8 vb = *reinterpret_cast<const bf16x8*>(&VT[dt * 16 + c16][kk2 * 32 + g * 8]);
        oacc[dt] = __builtin_amdgcn_mfma_f32_16x16x32_bf16(pa, vb, oacc[dt], 0, 0, 0);
      }
    }

#pragma unroll
    for (int dt = 0; dt < 3; ++dt)
#pragma unroll
      for (int r = 0; r < 4; ++r) {
        const int i = i0g + r;
        if (i < N_)
          out[((size_t)(b * N_ + i)) * C_ + h * 48 + dt * 16 + c16] = f2bf(oacc[dt][r]);
      }
  }
}

// ---------------- launch ----------------
extern "C" void kernel_launch(void* const* d_in, const int* in_sizes, int n_in,
                              void* d_out, int out_size, void* d_ws, size_t ws_size,
                              hipStream_t stream) {
  const size_t WS_NEEDED = 151487488;
  if (ws_size < WS_NEEDED) {
    fill_sentinel<<<512, 256, 0, stream>>>((float*)d_out, out_size);
    return;
  }

  const float* x      = (const float*)d_in[0];
  const float* n1w    = (const float*)d_in[1];
  const float* n1b    = (const float*)d_in[2];
  const float* qk_w   = (const float*)d_in[3];
  const float* v_w    = (const float*)d_in[4];
  const float* pos_w  = (const float*)d_in[5];
  const float* pos_b  = (const float*)d_in[6];
  const float* gating = (const float*)d_in[7];
  const float* proj_w = (const float*)d_in[8];
  const float* proj_b = (const float*)d_in[9];
  const float* n2w    = (const float*)d_in[10];
  const float* n2b    = (const float*)d_in[11];
  const float* fc1_w  = (const float*)d_in[12];
  const float* fc1_b  = (const float*)d_in[13];
  const float* fc2_w  = (const float*)d_in[14];
  const float* fc2_b  = (const float*)d_in[15];

  char* ws = (char*)d_ws;
  // workspace layout (bytes); total = 151,487,488
  u16*   xn    = (u16*)(ws + 0);          // 12544x768  bf16 (slot shared w/ xn2)
  u16*   xn2   = (u16*)(ws + 0);
  u16*   wqkv  = (u16*)(ws + 19267584);   // 2304x768   bf16
  u16*   wproj = (u16*)(ws + 22806528);   // 768x768    bf16
  u16*   wfc1  = (u16*)(ws + 23986176);   // 3072x768   bf16
  u16*   wfc2  = (u16*)(ws + 28704768);   // 768x3072   bf16
  float* pos   = (float*)(ws + 33423360); // 16x196x196 f32
  float* x1    = (float*)(ws + 35881984); // 12544x768  f32   -> ends 74417152
  u16*   qkv   = (u16*)(ws + 74417152);   // 12544x2304 bf16  -> ends 132219904
  u16*   attno = (u16*)(ws + 132219904);  // 12544x768  bf16  -> ends 151487488
  u16*   hbuf  = (u16*)(ws + 74417152);   // 12544x3072 bf16 (overlays qkv+attno)

  f2b4<<<512, 256, 0, stream>>>((const float4*)qk_w,   (ushort4*)wqkv,                (1536 * 768) / 4);
  f2b4<<<512, 256, 0, stream>>>((const float4*)v_w,    (ushort4*)(wqkv + 1536 * 768), (768 * 768) / 4);
  f2b4<<<512, 256, 0, stream>>>((const float4*)proj_w, (ushort4*)wproj,               (768 * 768) / 4);
  f2b4<<<512, 256, 0, stream>>>((const float4*)fc1_w,  (ushort4*)wfc1,                (3072 * 768) / 4);
  f2b4<<<512, 256, 0, stream>>>((const float4*)fc2_w,  (ushort4*)wfc2,                (768 * 3072) / 4);
  ln_rows<<<M_, 256, 0, stream>>>(x, n1w, n1b, xn);
  pos_softmax<<<dim3(196, 16), 64, 0, stream>>>(pos_w, pos_b, pos);
  gemm_bt<0><<<dim3(2304 / BN, M_ / BM), 256, 0, stream>>>(xn, wqkv, qkv, nullptr, nullptr, M_, 2304, 768);
  attn_mfma<<<B_ * H_, 512, 0, stream>>>(qkv, pos, gating, attno);
  gemm_bt<1><<<dim3(768 / BN, M_ / BM), 256, 0, stream>>>(attno, wproj, x1, proj_b, x, M_, 768, 768);
  ln_rows<<<M_, 256, 0, stream>>>(x1, n2w, n2b, xn2);
  gemm_bt<2><<<dim3(3072 / BN, M_ / BM), 256, 0, stream>>>(xn2, wfc1, hbuf, fc1_b, nullptr, M_, 3072, 768);
  gemm_bt<1><<<dim3(768 / BN, M_ / BM), 256, 0, stream>>>(hbuf, wfc2, (float*)d_out, fc2_b, x1, M_, 768, 3072);
}